// Round 1
// baseline (1082.183 us; speedup 1.0000x reference)
//
#include <hip/hip_runtime.h>
#include <math.h>

#define DEV_INLINE __device__ __forceinline__

typedef __attribute__((ext_vector_type(8))) short short8;
typedef __attribute__((ext_vector_type(4))) float f32x4;

constexpr int H = 128, W = 128, C = 128, B = 4;
constexpr int HWc = H * W;        // 16384
constexpr int KK = 9;
constexpr int KTOT = C * KK;      // 1152
constexpr int TPW = 16, TPH = 8, P = 128;   // positions per block
constexpr int KC = 32;                       // K-chunk (one MFMA K step)
constexpr int NCH = KTOT / KC;               // 36
constexpr int LDK = KC + 8;                  // padded LDS row stride (bf16)

DEV_INLINE unsigned short f2bf(float f) {
  union { float f; unsigned u; } v; v.f = f;
  unsigned r = v.u + 0x7FFFu + ((v.u >> 16) & 1u);   // RNE
  return (unsigned short)(r >> 16);
}

// MODE 0: plain conv, O=32 (18 offset ch + 9 mask ch + 5 pad), epilogue bias / 2*sigmoid
// MODE 1: deform conv, O=128, epilogue PReLU
// MODE 2: deform conv, O=128, epilogue BN2 + residual
template<int MODE>
__global__ __launch_bounds__(256, 2)
void gemm_kernel(const float* __restrict__ src,
                 const unsigned short* __restrict__ wb,   // [O][1152] bf16
                 const float* __restrict__ offs,          // (B,18,H,W) or null
                 const float* __restrict__ msk,           // (B,9,H,W) or null
                 const float* __restrict__ pA,
                 const float* __restrict__ pB,
                 const float* __restrict__ pM,
                 const float* __restrict__ pV,
                 const float* __restrict__ resid,
                 float* __restrict__ out0,
                 float* __restrict__ out1)
{
  constexpr int O = (MODE == 0) ? 32 : 128;
  __shared__ ushort4 sIdx[KK * P];                 // clamped corner indices (plane-local)
  __shared__ float4  sWt [KK * P];                 // bilinear weights * validity * mask
  __shared__ __attribute__((aligned(16))) unsigned short aT[O * LDK];
  __shared__ __attribute__((aligned(16))) unsigned short bT[P * LDK];

  const int tid = threadIdx.x;
  const int hx0 = blockIdx.x * TPW;
  const int hy0 = blockIdx.y * TPH;
  const int b   = blockIdx.z;

  // ---- per-(tap, position) sampling table (once per block) ----
  for (int i = tid; i < KK * P; i += 256) {
    const int kk = i >> 7;             // /128
    const int p  = i & 127;
    const int hy = hy0 + (p >> 4);
    const int hx = hx0 + (p & 15);
    const int ky = kk / 3, kx = kk - 3 * (kk / 3);
    float oy = 0.f, ox = 0.f, mv = 1.f;
    if (MODE != 0) {
      const size_t ob = ((size_t)(b * 18 + 2 * kk) * H + hy) * W + hx;
      oy = offs[ob];
      ox = offs[ob + (size_t)HWc];
      mv = msk[((size_t)(b * 9 + kk) * H + hy) * W + hx];
    }
    const float py = (float)(hy - 1 + ky) + oy;
    const float px = (float)(hx - 1 + kx) + ox;
    const float fy = floorf(py), fx = floorf(px);
    const float ay = py - fy, ax = px - fx;
    const int y0 = (int)fy, x0 = (int)fx;
    const int y1 = y0 + 1, x1 = x0 + 1;
    const bool vy0 = ((unsigned)y0 < (unsigned)H);
    const bool vy1 = ((unsigned)y1 < (unsigned)H);
    const bool vx0 = ((unsigned)x0 < (unsigned)W);
    const bool vx1 = ((unsigned)x1 < (unsigned)W);
    const int y0c = min(max(y0, 0), H - 1), y1c = min(max(y1, 0), H - 1);
    const int x0c = min(max(x0, 0), W - 1), x1c = min(max(x1, 0), W - 1);
    sIdx[i] = make_ushort4((unsigned short)(y0c * W + x0c),
                           (unsigned short)(y0c * W + x1c),
                           (unsigned short)(y1c * W + x0c),
                           (unsigned short)(y1c * W + x1c));
    const float wy0 = 1.f - ay, wx0 = 1.f - ax;
    sWt[i] = make_float4(wy0 * wx0 * ((vy0 && vx0) ? mv : 0.f),
                         wy0 * ax  * ((vy0 && vx1) ? mv : 0.f),
                         ay  * wx0 * ((vy1 && vx0) ? mv : 0.f),
                         ay  * ax  * ((vy1 && vx1) ? mv : 0.f));
  }

  f32x4 acc[O / 16][2];
  #pragma unroll
  for (int i = 0; i < O / 16; ++i) {
    acc[i][0] = (f32x4){0.f, 0.f, 0.f, 0.f};
    acc[i][1] = (f32x4){0.f, 0.f, 0.f, 0.f};
  }

  const int lane  = tid & 63;
  const int m16   = lane & 15;
  const int q     = lane >> 4;
  const int nbase = (tid >> 6) * 32;        // wave's 32-position slice
  const float* __restrict__ planes = src + (size_t)b * C * HWc;

  for (int ch = 0; ch < NCH; ++ch) {
    const int r0 = ch * KC;
    __syncthreads();
    // stage A tile: wb rows [0,O) cols [r0, r0+32) -> aT[o][kc]
    for (int i = tid; i < O * 4; i += 256) {
      const int o = i >> 2, cg = i & 3;
      *(float4*)(aT + o * LDK + cg * 8) =
          *(const float4*)(wb + (size_t)o * KTOT + r0 + cg * 8);
    }
    // stage B tile: bilinear samples -> bT[p][kc] (bf16)
    #pragma unroll
    for (int i = 0; i < 16; ++i) {
      const int e  = i * 256 + tid;
      const int kc = e >> 7;
      const int p  = e & 127;
      const int r  = r0 + kc;
      const int c  = (int)((unsigned)r / 9u);
      const int kk = r - 9 * c;
      const int si = (kk << 7) + p;
      const ushort4 id = sIdx[si];
      const float4  wt = sWt[si];
      const float* pl = planes + (size_t)c * HWc;
      const float v = wt.x * pl[id.x] + wt.y * pl[id.y]
                    + wt.z * pl[id.z] + wt.w * pl[id.w];
      bT[p * LDK + kc] = f2bf(v);
    }
    __syncthreads();
    // MFMA: D[o][p] += A[o][k] * B[k][p]
    const short8 bfr0 = *(const short8*)(bT + (nbase +      m16) * LDK + q * 8);
    const short8 bfr1 = *(const short8*)(bT + (nbase + 16 + m16) * LDK + q * 8);
    #pragma unroll
    for (int ot = 0; ot < O / 16; ++ot) {
      const short8 afr = *(const short8*)(aT + (ot * 16 + m16) * LDK + q * 8);
      acc[ot][0] = __builtin_amdgcn_mfma_f32_16x16x32_bf16(afr, bfr0, acc[ot][0], 0, 0, 0);
      acc[ot][1] = __builtin_amdgcn_mfma_f32_16x16x32_bf16(afr, bfr1, acc[ot][1], 0, 0, 0);
    }
  }

  // epilogue: D mapping col=lane&15 (p), row=(lane>>4)*4+reg (o)
  #pragma unroll
  for (int ot = 0; ot < O / 16; ++ot) {
    #pragma unroll
    for (int nt = 0; nt < 2; ++nt) {
      const int p  = nbase + nt * 16 + m16;
      const int hy = hy0 + (p >> 4);
      const int hx = hx0 + (p & 15);
      #pragma unroll
      for (int rg = 0; rg < 4; ++rg) {
        const int o = ot * 16 + q * 4 + rg;
        const float v = acc[ot][nt][rg];
        if (MODE == 0) {
          if (o < 18) {
            out0[((size_t)(b * 18 + o) * H + hy) * W + hx] = v + pA[o];
          } else if (o < 27) {
            const float z = v + pA[o];
            out1[((size_t)(b * 9 + (o - 18)) * H + hy) * W + hx] = 2.f / (1.f + expf(-z));
          }
        } else if (MODE == 1) {
          const size_t oi = ((size_t)(b * C + o) * H + hy) * W + hx;
          const float a = pA[o];
          out0[oi] = v > 0.f ? v : a * v;
        } else {
          const size_t oi = ((size_t)(b * C + o) * H + hy) * W + hx;
          const float s  = pA[o] * rsqrtf(pV[o] + 1e-5f);
          const float sh = pB[o] - pM[o] * s;
          out0[oi] = v * s + sh + resid[oi];
        }
      }
    }
  }
}

__global__ void bn1_kernel(const float* __restrict__ x,
                           const float* __restrict__ g, const float* __restrict__ bb,
                           const float* __restrict__ m, const float* __restrict__ v,
                           float* __restrict__ r1)
{
  const int i = blockIdx.x * 256 + threadIdx.x;   // float4 index, 2097152 total
  const int c = (i >> 12) & 127;                  // (i*4 / 16384) % 128
  const float s  = g[c] * rsqrtf(v[c] + 1e-5f);
  const float sh = bb[c] - m[c] * s;
  const float4 xv = ((const float4*)x)[i];
  float4 o;
  o.x = xv.x * s + sh; o.y = xv.y * s + sh;
  o.z = xv.z * s + sh; o.w = xv.w * s + sh;
  ((float4*)r1)[i] = o;
}

__global__ void prep_kernel(const float* __restrict__ w1, const float* __restrict__ w2,
                            const float* __restrict__ ow1, const float* __restrict__ mw1,
                            const float* __restrict__ ob1, const float* __restrict__ mb1,
                            const float* __restrict__ ow2, const float* __restrict__ mw2,
                            const float* __restrict__ ob2, const float* __restrict__ mb2,
                            unsigned short* __restrict__ wb1, unsigned short* __restrict__ wb2,
                            unsigned short* __restrict__ wom1, unsigned short* __restrict__ wom2,
                            float* __restrict__ bias1, float* __restrict__ bias2)
{
  const int i = blockIdx.x * 256 + threadIdx.x;   // 147456 threads
  if (i < 128 * KTOT) { wb1[i] = f2bf(w1[i]); wb2[i] = f2bf(w2[i]); }
  if (i < 32 * KTOT) {
    const int r = i / KTOT;
    unsigned short v1, v2;
    if (r < 18)      { v1 = f2bf(ow1[i]);             v2 = f2bf(ow2[i]); }
    else if (r < 27) { v1 = f2bf(mw1[i - 18 * KTOT]); v2 = f2bf(mw2[i - 18 * KTOT]); }
    else             { v1 = 0; v2 = 0; }
    wom1[i] = v1; wom2[i] = v2;
  }
  if (i < 32) {
    float b1, b2;
    if (i < 18)      { b1 = ob1[i];      b2 = ob2[i]; }
    else if (i < 27) { b1 = mb1[i - 18]; b2 = mb2[i - 18]; }
    else             { b1 = 0.f;         b2 = 0.f; }
    bias1[i] = b1; bias2[i] = b2;
  }
}

extern "C" void kernel_launch(void* const* d_in, const int* in_sizes, int n_in,
                              void* d_out, int out_size, void* d_ws, size_t ws_size,
                              hipStream_t stream)
{
  const float* x     = (const float*)d_in[0];
  const float* bn1g  = (const float*)d_in[1];
  const float* bn1b  = (const float*)d_in[2];
  const float* bn1m  = (const float*)d_in[3];
  const float* bn1v  = (const float*)d_in[4];
  const float* ow1   = (const float*)d_in[5];
  const float* ob1   = (const float*)d_in[6];
  const float* mw1   = (const float*)d_in[7];
  const float* mb1   = (const float*)d_in[8];
  const float* w1    = (const float*)d_in[9];
  const float* alpha = (const float*)d_in[10];
  const float* ow2   = (const float*)d_in[11];
  const float* ob2   = (const float*)d_in[12];
  const float* mw2   = (const float*)d_in[13];
  const float* mb2   = (const float*)d_in[14];
  const float* w2    = (const float*)d_in[15];
  const float* bn2g  = (const float*)d_in[16];
  const float* bn2b  = (const float*)d_in[17];
  const float* bn2m  = (const float*)d_in[18];
  const float* bn2v  = (const float*)d_in[19];
  float* out = (float*)d_out;

  char* wsp = (char*)d_ws;
  float* r1   = (float*)(wsp);                       // 33554432 B
  float* r2   = (float*)(wsp + 33554432);            // 33554432 B
  float* offb = (float*)(wsp + 67108864);            // 4718592 B
  float* mskb = (float*)(wsp + 71827456);            // 2359296 B
  unsigned short* wb1  = (unsigned short*)(wsp + 74186752);  // 294912 B
  unsigned short* wb2  = (unsigned short*)(wsp + 74481664);  // 294912 B
  unsigned short* wom1 = (unsigned short*)(wsp + 74776576);  // 73728 B
  unsigned short* wom2 = (unsigned short*)(wsp + 74850304);  // 73728 B
  float* bias1 = (float*)(wsp + 74924032);           // 128 B
  float* bias2 = (float*)(wsp + 74924160);           // 128 B

  prep_kernel<<<576, 256, 0, stream>>>(w1, w2, ow1, mw1, ob1, mb1,
                                       ow2, mw2, ob2, mb2,
                                       wb1, wb2, wom1, wom2, bias1, bias2);
  bn1_kernel<<<8192, 256, 0, stream>>>(x, bn1g, bn1b, bn1m, bn1v, r1);

  dim3 grid(W / TPW, H / TPH, B);   // 8 x 16 x 4 = 512 blocks
  gemm_kernel<0><<<grid, 256, 0, stream>>>(r1, wom1, nullptr, nullptr, bias1,
                                           nullptr, nullptr, nullptr, nullptr, offb, mskb);
  gemm_kernel<1><<<grid, 256, 0, stream>>>(r1, wb1, offb, mskb, alpha,
                                           nullptr, nullptr, nullptr, nullptr, r2, nullptr);
  gemm_kernel<0><<<grid, 256, 0, stream>>>(r2, wom2, nullptr, nullptr, bias2,
                                           nullptr, nullptr, nullptr, nullptr, offb, mskb);
  gemm_kernel<2><<<grid, 256, 0, stream>>>(r2, wb2, offb, mskb, bn2g,
                                           bn2b, bn2m, bn2v, x, out, nullptr);
}

// Round 2
// 626.322 us; speedup vs baseline: 1.7278x; 1.7278x over previous
//
#include <hip/hip_runtime.h>
#include <math.h>

#define DEV_INLINE __device__ __forceinline__

typedef __attribute__((ext_vector_type(8))) short short8;
typedef __attribute__((ext_vector_type(8))) unsigned short ushort8v;
typedef __attribute__((ext_vector_type(4))) float f32x4;

constexpr int H = 128, W = 128, C = 128, B = 4;
constexpr int HWc = H * W;        // 16384
constexpr int KK = 9;
constexpr int KT2 = 1184;         // 37 chunks * 32 (1152 real + 32 bn-shift/pad)
constexpr int P = 64;             // positions per block (one row segment)
constexpr int LDK = 40;           // padded LDS K stride (80 B, 16B-aligned rows)

DEV_INLINE unsigned short f2bf(float f) {
  union { float f; unsigned u; } v; v.f = f;
  unsigned r = v.u + 0x7FFFu + ((v.u >> 16) & 1u);   // RNE
  return (unsigned short)(r >> 16);
}
DEV_INLINE float bf2f(unsigned short u) {
  union { unsigned u; float f; } v; v.u = ((unsigned)u) << 16;
  return v.f;
}

// K ordering: k' = tap*128 + c  (tap-major). Chunk ch covers tap=ch/4,
// c in [(ch%4)*32, +32). Chunk 36 (BN only): bT = sum-of-bilinear-weights
// (or validity for MODE 0); A rows hold sum_c w[o][c][tap]*bnshift_c.
// MODE 0: plain conv, O=32 (18 offset + 9 mask + 5 pad). MODE 1: deform,
// PReLU out. MODE 2: deform, BN2+residual out.
template<int MODE, bool BN>
__global__ __launch_bounds__(256, 4)
void gemm2(const float* __restrict__ src,
           const unsigned short* __restrict__ wT,   // [O][1184] bf16, k' order
           const float* __restrict__ offs,
           const float* __restrict__ msk,
           const float* __restrict__ pA, const float* __restrict__ pB,
           const float* __restrict__ pM, const float* __restrict__ pV,
           const float* __restrict__ resid,
           float* __restrict__ out0, float* __restrict__ out1)
{
  constexpr int O  = (MODE == 0) ? 32 : 128;
  constexpr int NT = O / 16;
  __shared__ ushort4 sIdx[(MODE != 0) ? KK * P : 1];
  __shared__ ushort4 sWtb[(MODE != 0) ? KK * P : 1];
  __shared__ __attribute__((aligned(16))) unsigned short aT[O * LDK];
  __shared__ __attribute__((aligned(16))) unsigned short bT[P * LDK];

  const int tid = threadIdx.x;
  const int hx0 = blockIdx.x * P;
  const int hy  = blockIdx.y;
  const int b   = blockIdx.z;
  const float* __restrict__ srcB = src + (size_t)b * C * HWc;

  // ---- bilinear tables: per (tap, position), once per block ----
  if constexpr (MODE != 0) {
    for (int i = tid; i < KK * P; i += 256) {
      const int tap = i >> 6;
      const int pp  = i & 63;
      const int hx  = hx0 + pp;
      const int ky  = tap / 3, kx = tap - 3 * (tap / 3);
      const size_t ob = ((size_t)(b * 18 + 2 * tap) * H + hy) * W + hx;
      const float oy = offs[ob];
      const float ox = offs[ob + (size_t)HWc];
      const float mv = msk[((size_t)(b * 9 + tap) * H + hy) * W + hx];
      const float py = (float)(hy - 1 + ky) + oy;
      const float px = (float)(hx - 1 + kx) + ox;
      const float fy = floorf(py), fx = floorf(px);
      const float ay = py - fy, ax = px - fx;
      const int y0 = (int)fy, x0 = (int)fx;
      const int y1 = y0 + 1, x1 = x0 + 1;
      const bool vy0 = (unsigned)y0 < (unsigned)H, vy1 = (unsigned)y1 < (unsigned)H;
      const bool vx0 = (unsigned)x0 < (unsigned)W, vx1 = (unsigned)x1 < (unsigned)W;
      const int y0c = min(max(y0, 0), H - 1), y1c = min(max(y1, 0), H - 1);
      const int x0c = min(max(x0, 0), W - 1), x1c = min(max(x1, 0), W - 1);
      sIdx[i] = make_ushort4((unsigned short)(y0c * W + x0c),
                             (unsigned short)(y0c * W + x1c),
                             (unsigned short)(y1c * W + x0c),
                             (unsigned short)(y1c * W + x1c));
      const float wy0 = 1.f - ay, wx0 = 1.f - ax;
      sWtb[i] = make_ushort4(f2bf(wy0 * wx0 * ((vy0 && vx0) ? mv : 0.f)),
                             f2bf(wy0 * ax  * ((vy0 && vx1) ? mv : 0.f)),
                             f2bf(ay  * wx0 * ((vy1 && vx0) ? mv : 0.f)),
                             f2bf(ay  * ax  * ((vy1 && vx1) ? mv : 0.f)));
    }
  }

  f32x4 acc[NT];
  #pragma unroll
  for (int i = 0; i < NT; ++i) acc[i] = (f32x4){0.f, 0.f, 0.f, 0.f};

  const int lane = tid & 63;
  const int m16  = lane & 15;
  const int q    = lane >> 4;
  const int wid  = tid >> 6;
  const int p0   = wid << 4;
  const int p    = tid & 63;
  const int cg   = __builtin_amdgcn_readfirstlane(wid);   // wave-uniform

  constexpr int NCHT = BN ? 37 : 36;
  for (int ch = 0; ch < NCHT; ++ch) {
    __syncthreads();
    // A stage: [O][32] bf16, 16 B per thread-iter, coalesced
    for (int i = tid; i < O * 4; i += 256) {
      const int o = i >> 2, cgA = i & 3;
      *(float4*)(aT + o * LDK + cgA * 8) =
          *(const float4*)(wT + (size_t)o * KT2 + ch * 32 + cgA * 8);
    }
    // B stage: thread -> (p, 8 channels), one 16-B LDS store
    ushort8v rv;
    if (ch < 36) {
      if constexpr (MODE != 0) {
        const int tap = ch >> 2;
        const ushort4 id = sIdx[(tap << 6) + p];
        const ushort4 wt = sWtb[(tap << 6) + p];
        const float w0 = bf2f(wt.x), w1 = bf2f(wt.y);
        const float w2 = bf2f(wt.z), w3 = bf2f(wt.w);
        const int c = ((ch & 3) << 5) + (cg << 3);
        const float* pl = srcB + (size_t)c * HWc;
        #pragma unroll
        for (int j = 0; j < 8; ++j) {
          const float* qp = pl + (size_t)j * HWc;
          rv[j] = f2bf(w0 * qp[id.x] + w1 * qp[id.y] +
                       w2 * qp[id.z] + w3 * qp[id.w]);
        }
      } else {
        const int tap = ch >> 2;
        const int ky = tap / 3, kx = tap - 3 * (tap / 3);
        const int iy = hy + ky - 1;                 // block-uniform
        const int ix = hx0 + p + kx - 1;
        const bool vok = ((unsigned)iy < (unsigned)H) && ((unsigned)ix < (unsigned)W);
        const int c = ((ch & 3) << 5) + (cg << 3);
        const float* pl = srcB + (size_t)c * HWc + (iy * W + ix);
        #pragma unroll
        for (int j = 0; j < 8; ++j) {
          const float vv = vok ? pl[(size_t)j * HWc] : 0.f;
          rv[j] = f2bf(vv);
        }
      }
    } else {
      // BN shift chunk: column = sum of bilinear weights / validity
      #pragma unroll
      for (int j = 0; j < 8; ++j) {
        const int kj = (cg << 3) + j;
        float sv = 0.f;
        if (kj < KK) {
          if constexpr (MODE != 0) {
            const ushort4 wt = sWtb[(kj << 6) + p];
            sv = bf2f(wt.x) + bf2f(wt.y) + bf2f(wt.z) + bf2f(wt.w);
          } else {
            const int ky = kj / 3, kx = kj - 3 * (kj / 3);
            const int iy = hy + ky - 1, ix = hx0 + p + kx - 1;
            sv = (((unsigned)iy < (unsigned)H) && ((unsigned)ix < (unsigned)W)) ? 1.f : 0.f;
          }
        }
        rv[j] = f2bf(sv);
      }
    }
    *(ushort8v*)(bT + p * LDK + (cg << 3)) = rv;
    __syncthreads();
    // MFMA: D[o][p] += A[o][k] * B[p][k]
    const short8 bfr = *(const short8*)(bT + (p0 + m16) * LDK + (q << 3));
    #pragma unroll
    for (int ot = 0; ot < NT; ++ot) {
      const short8 afr = *(const short8*)(aT + (ot * 16 + m16) * LDK + (q << 3));
      acc[ot] = __builtin_amdgcn_mfma_f32_16x16x32_bf16(afr, bfr, acc[ot], 0, 0, 0);
    }
  }

  // epilogue: D col = lane&15 -> p, row = q*4+rg -> o
  const int hx = hx0 + p0 + m16;
  #pragma unroll
  for (int ot = 0; ot < NT; ++ot) {
    #pragma unroll
    for (int rg = 0; rg < 4; ++rg) {
      const int o = ot * 16 + (q << 2) + rg;
      const float vv = acc[ot][rg];
      if constexpr (MODE == 0) {
        if (o < 18) {
          out0[((size_t)(b * 18 + o) * H + hy) * W + hx] = vv + pA[o];
        } else if (o < 27) {
          const float z = vv + pA[o];
          out1[((size_t)(b * 9 + (o - 18)) * H + hy) * W + hx] = 2.f / (1.f + expf(-z));
        }
      } else if constexpr (MODE == 1) {
        const size_t oi = ((size_t)(b * C + o) * H + hy) * W + hx;
        const float a = pA[o];
        out0[oi] = vv > 0.f ? vv : a * vv;
      } else {
        const size_t oi = ((size_t)(b * C + o) * H + hy) * W + hx;
        const float s  = pA[o] * rsqrtf(pV[o] + 1e-5f);
        const float sh = pB[o] - pM[o] * s;
        out0[oi] = vv * s + sh + resid[oi];
      }
    }
  }
}

__global__ void prep2(const float* __restrict__ w1, const float* __restrict__ w2,
                      const float* __restrict__ ow1, const float* __restrict__ mw1,
                      const float* __restrict__ ob1, const float* __restrict__ mb1,
                      const float* __restrict__ ow2, const float* __restrict__ mw2,
                      const float* __restrict__ ob2, const float* __restrict__ mb2,
                      const float* __restrict__ g, const float* __restrict__ bb,
                      const float* __restrict__ m, const float* __restrict__ v,
                      unsigned short* __restrict__ wb1, unsigned short* __restrict__ wb2,
                      unsigned short* __restrict__ wom1, unsigned short* __restrict__ wom2,
                      float* __restrict__ bias1, float* __restrict__ bias2)
{
  const int i = blockIdx.x * 256 + threadIdx.x;
  if (i < 128 * KT2) {
    const int o = i / KT2, kp = i - o * KT2;
    unsigned short v1 = 0, v2 = 0;
    if (kp < 1152) {
      const int c = kp & 127, kk = kp >> 7;
      const float s = g[c] * rsqrtf(v[c] + 1e-5f);
      v1 = f2bf(w1[(size_t)(o * 128 + c) * 9 + kk] * s);   // BN scale folded (layer 1)
      v2 = f2bf(w2[(size_t)(o * 128 + c) * 9 + kk]);
    } else if (kp < 1152 + KK) {
      const int kk = kp - 1152;
      float acc = 0.f;
      for (int c = 0; c < 128; ++c) {
        const float s  = g[c] * rsqrtf(v[c] + 1e-5f);
        const float sh = bb[c] - m[c] * s;
        acc += w1[(size_t)(o * 128 + c) * 9 + kk] * sh;    // BN shift column
      }
      v1 = f2bf(acc);
    }
    wb1[i] = v1; wb2[i] = v2;
  }
  if (i < 32 * KT2) {
    const int o = i / KT2, kp = i - o * KT2;
    unsigned short v1 = 0, v2 = 0;
    if (kp < 1152) {
      const int c = kp & 127, kk = kp >> 7;
      const float s = g[c] * rsqrtf(v[c] + 1e-5f);
      if (o < 18) {
        v1 = f2bf(ow1[(size_t)(o * 128 + c) * 9 + kk] * s);
        v2 = f2bf(ow2[(size_t)(o * 128 + c) * 9 + kk]);
      } else if (o < 27) {
        v1 = f2bf(mw1[(size_t)((o - 18) * 128 + c) * 9 + kk] * s);
        v2 = f2bf(mw2[(size_t)((o - 18) * 128 + c) * 9 + kk]);
      }
    } else if (kp < 1152 + KK && o < 27) {
      const int kk = kp - 1152;
      const float* wsrc = (o < 18) ? ow1 + (size_t)o * 1152
                                   : mw1 + (size_t)(o - 18) * 1152;
      float acc = 0.f;
      for (int c = 0; c < 128; ++c) {
        const float s  = g[c] * rsqrtf(v[c] + 1e-5f);
        const float sh = bb[c] - m[c] * s;
        acc += wsrc[(size_t)c * 9 + kk] * sh;
      }
      v1 = f2bf(acc);
    }
    wom1[i] = v1; wom2[i] = v2;
  }
  if (i < 32) {
    float b1 = 0.f, b2 = 0.f;
    if (i < 18)      { b1 = ob1[i];      b2 = ob2[i]; }
    else if (i < 27) { b1 = mb1[i - 18]; b2 = mb2[i - 18]; }
    bias1[i] = b1; bias2[i] = b2;
  }
}

extern "C" void kernel_launch(void* const* d_in, const int* in_sizes, int n_in,
                              void* d_out, int out_size, void* d_ws, size_t ws_size,
                              hipStream_t stream)
{
  const float* x     = (const float*)d_in[0];
  const float* bn1g  = (const float*)d_in[1];
  const float* bn1b  = (const float*)d_in[2];
  const float* bn1m  = (const float*)d_in[3];
  const float* bn1v  = (const float*)d_in[4];
  const float* ow1   = (const float*)d_in[5];
  const float* ob1   = (const float*)d_in[6];
  const float* mw1   = (const float*)d_in[7];
  const float* mb1   = (const float*)d_in[8];
  const float* w1    = (const float*)d_in[9];
  const float* alpha = (const float*)d_in[10];
  const float* ow2   = (const float*)d_in[11];
  const float* ob2   = (const float*)d_in[12];
  const float* mw2   = (const float*)d_in[13];
  const float* mb2   = (const float*)d_in[14];
  const float* w2    = (const float*)d_in[15];
  const float* bn2g  = (const float*)d_in[16];
  const float* bn2b  = (const float*)d_in[17];
  const float* bn2m  = (const float*)d_in[18];
  const float* bn2v  = (const float*)d_in[19];
  float* out = (float*)d_out;

  char* wsp = (char*)d_ws;
  float* r2   = (float*)(wsp);                               // 33554432 B
  float* offb = (float*)(wsp + 33554432);                    // 4718592 B
  float* mskb = (float*)(wsp + 38273024);                    // 2359296 B
  unsigned short* wb1  = (unsigned short*)(wsp + 40632320);  // 303104 B
  unsigned short* wb2  = (unsigned short*)(wsp + 40935424);  // 303104 B
  unsigned short* wom1 = (unsigned short*)(wsp + 41238528);  // 75776 B
  unsigned short* wom2 = (unsigned short*)(wsp + 41314304);  // 75776 B
  float* bias1 = (float*)(wsp + 41390080);
  float* bias2 = (float*)(wsp + 41390208);

  prep2<<<(128 * KT2 + 255) / 256, 256, 0, stream>>>(
      w1, w2, ow1, mw1, ob1, mb1, ow2, mw2, ob2, mb2,
      bn1g, bn1b, bn1m, bn1v, wb1, wb2, wom1, wom2, bias1, bias2);

  dim3 grid(W / P, H, B);   // 2 x 128 x 4 = 1024 blocks -> 4 per CU
  gemm2<0, true><<<grid, 256, 0, stream>>>(x, wom1, nullptr, nullptr, bias1,
      nullptr, nullptr, nullptr, nullptr, offb, mskb);
  gemm2<1, true><<<grid, 256, 0, stream>>>(x, wb1, offb, mskb, alpha,
      nullptr, nullptr, nullptr, nullptr, r2, nullptr);
  gemm2<0, false><<<grid, 256, 0, stream>>>(r2, wom2, nullptr, nullptr, bias2,
      nullptr, nullptr, nullptr, nullptr, offb, mskb);
  gemm2<2, false><<<grid, 256, 0, stream>>>(r2, wb2, offb, mskb, bn2g,
      bn2b, bn2m, bn2v, x, out, nullptr);
}

// Round 3
// 617.516 us; speedup vs baseline: 1.7525x; 1.0143x over previous
//
#include <hip/hip_runtime.h>
#include <math.h>

#define DEV_INLINE __device__ __forceinline__

typedef __attribute__((ext_vector_type(8))) short short8;
typedef __attribute__((ext_vector_type(8))) unsigned short ushort8v;
typedef __attribute__((ext_vector_type(4))) float f32x4;

constexpr int H = 128, W = 128, C = 128, B = 4;
constexpr int HWc = H * W;        // 16384
constexpr int KK = 9;
constexpr int KT2 = 1184;         // 37 chunks * 32
constexpr int P = 64;             // positions per block (one row segment)
constexpr int LDK = 40;           // padded LDS K stride

DEV_INLINE unsigned short f2bf(float f) {
  union { float f; unsigned u; } v; v.f = f;
  unsigned r = v.u + 0x7FFFu + ((v.u >> 16) & 1u);   // RNE
  return (unsigned short)(r >> 16);
}
DEV_INLINE float bf2f(unsigned short u) {
  union { unsigned u; float f; } v; v.u = ((unsigned)u) << 16;
  return v.f;
}

// K order: chunk ch in [0,36): cg = ch/9, tap = ch%9; k covers channels
// c = cg*32 + [0,32) at that tap (channel-group-major => 9-tap L1 reuse of
// each 32-channel source slice). Chunk 36: BN-shift column (layer 1 only).
// Grid: 1024 1-D blocks; blk&7 selects an XCD-stripe (b, 64-row band) so each
// XCD's L2 holds one 2.1 MB bf16 stripe.
// MODE 0: plain conv, O=32 (18 offset + 9 mask + 5 pad), fp32 outputs.
// MODE 1: deform conv, O=128, PReLU -> bf16 out.
// MODE 2: deform conv, O=128, BN2 + fp32 residual -> fp32 out.
template<int MODE, bool BN>
__global__ __launch_bounds__(256, 4)
void gemm2(const unsigned short* __restrict__ src,      // bf16 (B,C,H,W)
           const unsigned short* __restrict__ wT,       // [O][1184] bf16
           const float* __restrict__ offs,
           const float* __restrict__ msk,
           const float* __restrict__ pA, const float* __restrict__ pB,
           const float* __restrict__ pM, const float* __restrict__ pV,
           const float* __restrict__ resid,
           float* __restrict__ outf,                    // MODE 0 offs / MODE 2 out
           unsigned short* __restrict__ outh,           // MODE 1 bf16 out
           float* __restrict__ out1)                    // MODE 0 mask
{
  constexpr int O  = (MODE == 0) ? 32 : 128;
  constexpr int NT = O / 16;
  __shared__ ushort4 sIdx[(MODE != 0) ? KK * P : 1];
  __shared__ ushort4 sWtb[(MODE != 0) ? KK * P : 1];
  __shared__ __attribute__((aligned(16))) unsigned short aT[O * LDK];
  __shared__ __attribute__((aligned(16))) unsigned short bT[P * LDK];

  const int tid = threadIdx.x;
  // XCD-stripe swizzle (blk%8 -> XCD is the usual round-robin mapping;
  // perf heuristic only, correctness independent of it)
  const int raw  = blockIdx.x;
  const int xcd  = raw & 7;
  const int slot = raw >> 3;                 // [0,128)
  const int b    = xcd >> 1;
  const int hy   = ((xcd & 1) << 6) | (slot >> 1);
  const int hx0  = (slot & 1) << 6;
  const unsigned short* __restrict__ srcB = src + (size_t)b * C * HWc;

  // ---- bilinear tables: per (tap, position), once per block ----
  if constexpr (MODE != 0) {
    for (int i = tid; i < KK * P; i += 256) {
      const int tap = i >> 6;
      const int pp  = i & 63;
      const int hx  = hx0 + pp;
      const int ky  = tap / 3, kx = tap - 3 * (tap / 3);
      const size_t ob = ((size_t)(b * 18 + 2 * tap) * H + hy) * W + hx;
      const float oy = offs[ob];
      const float ox = offs[ob + (size_t)HWc];
      const float mv = msk[((size_t)(b * 9 + tap) * H + hy) * W + hx];
      const float py = (float)(hy - 1 + ky) + oy;
      const float px = (float)(hx - 1 + kx) + ox;
      const float fy = floorf(py), fx = floorf(px);
      const float ay = py - fy, ax = px - fx;
      const int y0 = (int)fy, x0 = (int)fx;
      const int y1 = y0 + 1, x1 = x0 + 1;
      const bool vy0 = (unsigned)y0 < (unsigned)H, vy1 = (unsigned)y1 < (unsigned)H;
      const bool vx0 = (unsigned)x0 < (unsigned)W, vx1 = (unsigned)x1 < (unsigned)W;
      const int y0c = min(max(y0, 0), H - 1), y1c = min(max(y1, 0), H - 1);
      const int x0c = min(max(x0, 0), W - 1), x1c = min(max(x1, 0), W - 1);
      sIdx[i] = make_ushort4((unsigned short)(y0c * W + x0c),
                             (unsigned short)(y0c * W + x1c),
                             (unsigned short)(y1c * W + x0c),
                             (unsigned short)(y1c * W + x1c));
      const float wy0 = 1.f - ay, wx0 = 1.f - ax;
      sWtb[i] = make_ushort4(f2bf(wy0 * wx0 * ((vy0 && vx0) ? mv : 0.f)),
                             f2bf(wy0 * ax  * ((vy0 && vx1) ? mv : 0.f)),
                             f2bf(ay  * wx0 * ((vy1 && vx0) ? mv : 0.f)),
                             f2bf(ay  * ax  * ((vy1 && vx1) ? mv : 0.f)));
    }
  }

  f32x4 acc[NT];
  #pragma unroll
  for (int i = 0; i < NT; ++i) acc[i] = (f32x4){0.f, 0.f, 0.f, 0.f};

  const int lane = tid & 63;
  const int m16  = lane & 15;
  const int q    = lane >> 4;
  const int wid  = tid >> 6;
  const int p0   = wid << 4;
  const int p    = tid & 63;

  constexpr int NCHT = BN ? 37 : 36;
  for (int ch = 0; ch < NCHT; ++ch) {
    __syncthreads();
    // A stage
    for (int i = tid; i < O * 4; i += 256) {
      const int o = i >> 2, cgA = i & 3;
      *(float4*)(aT + o * LDK + cgA * 8) =
          *(const float4*)(wT + (size_t)o * KT2 + ch * 32 + cgA * 8);
    }
    // B stage
    ushort8v rv;
    if (ch < 36) {
      const int cg  = ch / 9;
      const int tap = ch - 9 * cg;
      const int c   = (cg << 5) + (wid << 3);
      if constexpr (MODE != 0) {
        const ushort4 id = sIdx[(tap << 6) + p];
        const ushort4 wt = sWtb[(tap << 6) + p];
        const float w0 = bf2f(wt.x), w1 = bf2f(wt.y);
        const float w2 = bf2f(wt.z), w3 = bf2f(wt.w);
        const unsigned short* pl = srcB + (size_t)c * HWc;
        #pragma unroll
        for (int j = 0; j < 8; ++j) {
          const unsigned short* qp = pl + (size_t)j * HWc;
          rv[j] = f2bf(w0 * bf2f(qp[id.x]) + w1 * bf2f(qp[id.y]) +
                       w2 * bf2f(qp[id.z]) + w3 * bf2f(qp[id.w]));
        }
      } else {
        const int ky = tap / 3, kx = tap - 3 * (tap / 3);
        const int iy = hy + ky - 1;
        const int ix = hx0 + p + kx - 1;
        const bool vok = ((unsigned)iy < (unsigned)H) && ((unsigned)ix < (unsigned)W);
        const unsigned short* pl = srcB + (size_t)c * HWc + (iy * W + ix);
        #pragma unroll
        for (int j = 0; j < 8; ++j)
          rv[j] = vok ? pl[(size_t)j * HWc] : (unsigned short)0;
      }
    } else {
      // BN shift chunk
      #pragma unroll
      for (int j = 0; j < 8; ++j) {
        const int kj = (wid << 3) + j;
        float sv = 0.f;
        if (kj < KK) {
          if constexpr (MODE != 0) {
            const ushort4 wt = sWtb[(kj << 6) + p];
            sv = bf2f(wt.x) + bf2f(wt.y) + bf2f(wt.z) + bf2f(wt.w);
          } else {
            const int ky = kj / 3, kx = kj - 3 * (kj / 3);
            const int iy = hy + ky - 1, ix = hx0 + p + kx - 1;
            sv = (((unsigned)iy < (unsigned)H) && ((unsigned)ix < (unsigned)W)) ? 1.f : 0.f;
          }
        }
        rv[j] = f2bf(sv);
      }
    }
    *(ushort8v*)(bT + p * LDK + (wid << 3)) = rv;
    __syncthreads();
    // MFMA
    const short8 bfr = *(const short8*)(bT + (p0 + m16) * LDK + (q << 3));
    #pragma unroll
    for (int ot = 0; ot < NT; ++ot) {
      const short8 afr = *(const short8*)(aT + (ot * 16 + m16) * LDK + (q << 3));
      acc[ot] = __builtin_amdgcn_mfma_f32_16x16x32_bf16(afr, bfr, acc[ot], 0, 0, 0);
    }
  }

  // epilogue: D col = lane&15 -> p, row = q*4+rg -> o
  const int hx = hx0 + p0 + m16;
  #pragma unroll
  for (int ot = 0; ot < NT; ++ot) {
    #pragma unroll
    for (int rg = 0; rg < 4; ++rg) {
      const int o = ot * 16 + (q << 2) + rg;
      const float vv = acc[ot][rg];
      if constexpr (MODE == 0) {
        if (o < 18) {
          outf[((size_t)(b * 18 + o) * H + hy) * W + hx] = vv + pA[o];
        } else if (o < 27) {
          const float z = vv + pA[o];
          out1[((size_t)(b * 9 + (o - 18)) * H + hy) * W + hx] = 2.f / (1.f + expf(-z));
        }
      } else if constexpr (MODE == 1) {
        const size_t oi = ((size_t)(b * C + o) * H + hy) * W + hx;
        const float a = pA[o];
        outh[oi] = f2bf(vv > 0.f ? vv : a * vv);
      } else {
        const size_t oi = ((size_t)(b * C + o) * H + hy) * W + hx;
        const float s  = pA[o] * rsqrtf(pV[o] + 1e-5f);
        const float sh = pB[o] - pM[o] * s;
        outf[oi] = vv * s + sh + resid[oi];
      }
    }
  }
}

__global__ void xcvt(const float* __restrict__ x, unsigned short* __restrict__ xb)
{
  const int i = blockIdx.x * 256 + threadIdx.x;   // 2097152 float4 groups
  const float4 v = ((const float4*)x)[i];
  ushort4 o;
  o.x = f2bf(v.x); o.y = f2bf(v.y); o.z = f2bf(v.z); o.w = f2bf(v.w);
  *(ushort4*)(xb + (size_t)i * 4) = o;
}

__global__ void prep2(const float* __restrict__ w1, const float* __restrict__ w2,
                      const float* __restrict__ ow1, const float* __restrict__ mw1,
                      const float* __restrict__ ob1, const float* __restrict__ mb1,
                      const float* __restrict__ ow2, const float* __restrict__ mw2,
                      const float* __restrict__ ob2, const float* __restrict__ mb2,
                      const float* __restrict__ g, const float* __restrict__ bb,
                      const float* __restrict__ m, const float* __restrict__ v,
                      unsigned short* __restrict__ wb1, unsigned short* __restrict__ wb2,
                      unsigned short* __restrict__ wom1, unsigned short* __restrict__ wom2,
                      float* __restrict__ bias1, float* __restrict__ bias2)
{
  const int i = blockIdx.x * 256 + threadIdx.x;
  if (i < 128 * KT2) {
    const int o = i / KT2, kp = i - o * KT2;
    unsigned short v1 = 0, v2 = 0;
    if (kp < 1152) {
      const int chn = kp >> 5, j = kp & 31;
      const int cg = chn / 9, tap = chn - 9 * cg;
      const int c = (cg << 5) + j;
      const float s = g[c] * rsqrtf(v[c] + 1e-5f);
      v1 = f2bf(w1[(size_t)(o * 128 + c) * 9 + tap] * s);
      v2 = f2bf(w2[(size_t)(o * 128 + c) * 9 + tap]);
    } else if (kp < 1152 + KK) {
      const int kk = kp - 1152;
      float acc = 0.f;
      for (int c = 0; c < 128; ++c) {
        const float s  = g[c] * rsqrtf(v[c] + 1e-5f);
        const float sh = bb[c] - m[c] * s;
        acc += w1[(size_t)(o * 128 + c) * 9 + kk] * sh;
      }
      v1 = f2bf(acc);
    }
    wb1[i] = v1; wb2[i] = v2;
  }
  if (i < 32 * KT2) {
    const int o = i / KT2, kp = i - o * KT2;
    unsigned short v1 = 0, v2 = 0;
    if (kp < 1152) {
      const int chn = kp >> 5, j = kp & 31;
      const int cg = chn / 9, tap = chn - 9 * cg;
      const int c = (cg << 5) + j;
      const float s = g[c] * rsqrtf(v[c] + 1e-5f);
      if (o < 18) {
        v1 = f2bf(ow1[(size_t)(o * 128 + c) * 9 + tap] * s);
        v2 = f2bf(ow2[(size_t)(o * 128 + c) * 9 + tap]);
      } else if (o < 27) {
        v1 = f2bf(mw1[(size_t)((o - 18) * 128 + c) * 9 + tap] * s);
        v2 = f2bf(mw2[(size_t)((o - 18) * 128 + c) * 9 + tap]);
      }
    } else if (kp < 1152 + KK && o < 27) {
      const int kk = kp - 1152;
      const float* wsrc = (o < 18) ? ow1 + (size_t)o * 1152
                                   : mw1 + (size_t)(o - 18) * 1152;
      float acc = 0.f;
      for (int c = 0; c < 128; ++c) {
        const float s  = g[c] * rsqrtf(v[c] + 1e-5f);
        const float sh = bb[c] - m[c] * s;
        acc += wsrc[(size_t)c * 9 + kk] * sh;
      }
      v1 = f2bf(acc);
    }
    wom1[i] = v1; wom2[i] = v2;
  }
  if (i < 32) {
    float b1 = 0.f, b2 = 0.f;
    if (i < 18)      { b1 = ob1[i];      b2 = ob2[i]; }
    else if (i < 27) { b1 = mb1[i - 18]; b2 = mb2[i - 18]; }
    bias1[i] = b1; bias2[i] = b2;
  }
}

extern "C" void kernel_launch(void* const* d_in, const int* in_sizes, int n_in,
                              void* d_out, int out_size, void* d_ws, size_t ws_size,
                              hipStream_t stream)
{
  const float* x     = (const float*)d_in[0];
  const float* bn1g  = (const float*)d_in[1];
  const float* bn1b  = (const float*)d_in[2];
  const float* bn1m  = (const float*)d_in[3];
  const float* bn1v  = (const float*)d_in[4];
  const float* ow1   = (const float*)d_in[5];
  const float* ob1   = (const float*)d_in[6];
  const float* mw1   = (const float*)d_in[7];
  const float* mb1   = (const float*)d_in[8];
  const float* w1    = (const float*)d_in[9];
  const float* alpha = (const float*)d_in[10];
  const float* ow2   = (const float*)d_in[11];
  const float* ob2   = (const float*)d_in[12];
  const float* mw2   = (const float*)d_in[13];
  const float* mb2   = (const float*)d_in[14];
  const float* w2    = (const float*)d_in[15];
  const float* bn2g  = (const float*)d_in[16];
  const float* bn2b  = (const float*)d_in[17];
  const float* bn2m  = (const float*)d_in[18];
  const float* bn2v  = (const float*)d_in[19];
  float* out = (float*)d_out;

  char* wsp = (char*)d_ws;
  unsigned short* xbf  = (unsigned short*)(wsp);             // 16777216 B
  unsigned short* r2bf = (unsigned short*)(wsp + 16777216);  // 16777216 B
  float* offb = (float*)(wsp + 33554432);                    // 4718592 B
  float* mskb = (float*)(wsp + 38273024);                    // 2359296 B
  unsigned short* wb1  = (unsigned short*)(wsp + 40632320);  // 303104 B
  unsigned short* wb2  = (unsigned short*)(wsp + 40935424);  // 303104 B
  unsigned short* wom1 = (unsigned short*)(wsp + 41238528);  // 75776 B
  unsigned short* wom2 = (unsigned short*)(wsp + 41314304);  // 75776 B
  float* bias1 = (float*)(wsp + 41390080);
  float* bias2 = (float*)(wsp + 41390208);

  xcvt<<<8192, 256, 0, stream>>>(x, xbf);
  prep2<<<(128 * KT2 + 255) / 256, 256, 0, stream>>>(
      w1, w2, ow1, mw1, ob1, mb1, ow2, mw2, ob2, mb2,
      bn1g, bn1b, bn1m, bn1v, wb1, wb2, wom1, wom2, bias1, bias2);

  dim3 grid(1024);
  gemm2<0, true><<<grid, 256, 0, stream>>>(xbf, wom1, nullptr, nullptr, bias1,
      nullptr, nullptr, nullptr, nullptr, offb, nullptr, mskb);
  gemm2<1, true><<<grid, 256, 0, stream>>>(xbf, wb1, offb, mskb, alpha,
      nullptr, nullptr, nullptr, nullptr, nullptr, r2bf, nullptr);
  gemm2<0, false><<<grid, 256, 0, stream>>>(r2bf, wom2, nullptr, nullptr, bias2,
      nullptr, nullptr, nullptr, nullptr, offb, nullptr, mskb);
  gemm2<2, false><<<grid, 256, 0, stream>>>(r2bf, wb2, offb, mskb, bn2g,
      bn2b, bn2m, bn2v, x, out, nullptr, nullptr);
}